// Round 1
// baseline (1492.872 us; speedup 1.0000x reference)
//
#include <hip/hip_runtime.h>
#include <stdint.h>

#define D_MODEL 768
#define BATCH   16
#define SEQ     2048
#define M_ROWS  (BATCH * SEQ)   // 32768
#define LN_EPS  1e-5f

typedef __attribute__((ext_vector_type(4))) float  f32x4;
typedef __attribute__((ext_vector_type(8))) __bf16 bf16x8;

__device__ __forceinline__ unsigned short f2bf(float f) {
    union { float f; uint32_t u; } v; v.f = f;
    uint32_t u = v.u;
    uint32_t r = (u + 0x7FFFu + ((u >> 16) & 1u)) >> 16;   // RNE
    return (unsigned short)r;
}

__device__ __forceinline__ void gload_lds16(const void* g, void* l) {
    __builtin_amdgcn_global_load_lds(
        (const __attribute__((address_space(1))) unsigned int*)g,
        (__attribute__((address_space(3))) unsigned int*)l,
        16, 0, 0);
}

// ---------------- Kernel 1: convert x -> bf16, fused decay GEMV ----------------
__global__ __launch_bounds__(256) void k_conv_decay(
    const float* __restrict__ x, const float* __restrict__ Wd,
    const float* __restrict__ bd, unsigned short* __restrict__ xb,
    float* __restrict__ decay)
{
    int row = blockIdx.x;
    int i   = threadIdx.x;
    const float* xr = x + (size_t)row * D_MODEL;
    float v0 = xr[i], v1 = xr[i + 256], v2 = xr[i + 512];
    unsigned short* xbr = xb + (size_t)row * D_MODEL;
    xbr[i] = f2bf(v0); xbr[i + 256] = f2bf(v1); xbr[i + 512] = f2bf(v2);

    float part = v0 * Wd[i] + v1 * Wd[i + 256] + v2 * Wd[i + 512];
    #pragma unroll
    for (int off = 32; off; off >>= 1) part += __shfl_down(part, off);
    __shared__ float wsum[4];
    int wid = i >> 6, lane = i & 63;
    if (lane == 0) wsum[wid] = part;
    __syncthreads();
    if (i == 0) {
        float s = wsum[0] + wsum[1] + wsum[2] + wsum[3] + bd[0];
        decay[row] = 1.f / (1.f + __expf(-s));
    }
}

// ---------------- Kernel 2: convert both weight matrices to bf16 ----------------
__global__ __launch_bounds__(256) void k_conv_w(
    const float* __restrict__ Wb, const float* __restrict__ Wi,
    unsigned short* __restrict__ WbB, unsigned short* __restrict__ WiB)
{
    const int NW = D_MODEL * D_MODEL;          // 589824
    int g = blockIdx.x * 256 + threadIdx.x;
    int base = g * 4;
    const float* src; unsigned short* dst;
    if (base < NW) { src = Wb + base; dst = WbB + base; }
    else           { base -= NW; src = Wi + base; dst = WiB + base; }
    float4 v = *(const float4*)src;
    ushort4 o;
    o.x = f2bf(v.x); o.y = f2bf(v.y); o.z = f2bf(v.z); o.w = f2bf(v.w);
    *(ushort4*)dst = o;
}

// ---------------- Kernel 3: bf16 MFMA GEMM, C(M,N) = A(M,K) * B(N,K)^T + bias ----------------
#define BM 128
#define BN 128
#define BK 32

__global__ __launch_bounds__(256) void k_gemm_bt(
    const unsigned short* __restrict__ A,   // (M,K) bf16
    const unsigned short* __restrict__ B,   // (N,K) bf16  (== W row-major)
    const float* __restrict__ bias,         // (N)
    float* __restrict__ C)                  // (M,N) f32
{
    const int K = D_MODEL, N = D_MODEL;
    __shared__ unsigned short As[BM * BK];  // 8 KiB
    __shared__ unsigned short Bs[BN * BK];  // 8 KiB

    int tid  = threadIdx.x;
    int wave = tid >> 6, lane = tid & 63;
    int m0 = blockIdx.y * BM, n0 = blockIdx.x * BN;
    int wm = wave >> 1, wn = wave & 1;      // 2x2 wave grid, 64x64 per wave

    f32x4 acc[4][4] = {};

    for (int k0 = 0; k0 < K; k0 += BK) {
        // stage A,B tiles: 512 16B-chunks each; wave w handles chunks [w*128, w*128+128)
        #pragma unroll
        for (int hh = 0; hh < 2; ++hh) {
            int c  = wave * 128 + hh * 64 + lane;
            int r  = c >> 2;
            int k8 = (c & 3) * 8;
            gload_lds16(A + (size_t)(m0 + r) * K + k0 + k8, (char*)As + c * 16);
            gload_lds16(B + (size_t)(n0 + r) * K + k0 + k8, (char*)Bs + c * 16);
        }
        __syncthreads();

        bf16x8 af[4], bfr[4];
        int kl = (lane >> 4) * 8;
        int rl = lane & 15;
        #pragma unroll
        for (int i = 0; i < 4; ++i) {
            af[i]  = *reinterpret_cast<const bf16x8*>(&As[(wm * 64 + i * 16 + rl) * BK + kl]);
            bfr[i] = *reinterpret_cast<const bf16x8*>(&Bs[(wn * 64 + i * 16 + rl) * BK + kl]);
        }
        #pragma unroll
        for (int i = 0; i < 4; ++i)
            #pragma unroll
            for (int j = 0; j < 4; ++j)
                acc[i][j] = __builtin_amdgcn_mfma_f32_16x16x32_bf16(af[i], bfr[j], acc[i][j], 0, 0, 0);
        __syncthreads();
    }

    // epilogue: C/D layout col=lane&15, row=(lane>>4)*4+reg
    int cl = lane & 15;
    int rg = (lane >> 4) * 4;
    #pragma unroll
    for (int j = 0; j < 4; ++j) {
        int col = n0 + wn * 64 + j * 16 + cl;
        float bs = bias[col];
        #pragma unroll
        for (int i = 0; i < 4; ++i) {
            int rowb = m0 + wm * 64 + i * 16 + rg;
            #pragma unroll
            for (int r = 0; r < 4; ++r)
                C[(size_t)(rowb + r) * N + col] = acc[i][j][r] + bs;
        }
    }
}

// ---------------- Kernel 4: sequential scan, one thread per (batch, 3-block) chain ----------------
#define PF 8
__global__ __launch_bounds__(64) void k_scan(
    const float* __restrict__ biv,    // (B,S,768) f32
    const float* __restrict__ decay,  // (B,S)
    float* __restrict__ io)           // in: inj (B,S,768); out: h (in place)
{
    int tid = blockIdx.x * 64 + threadIdx.x;   // 0..4095
    int b = tid >> 8;
    int j = tid & 255;
    const float* bv = biv + (size_t)b * SEQ * D_MODEL + j * 3;
    float*       po = io  + (size_t)b * SEQ * D_MODEL + j * 3;
    const float* dk = decay + b * SEQ;

    float pbx[PF], pby[PF], pbz[PF], pix[PF], piy[PF], piz[PF], pd[PF];
    #pragma unroll
    for (int p = 0; p < PF; ++p) {
        size_t o = (size_t)p * D_MODEL;
        pbx[p] = bv[o + 0]; pby[p] = bv[o + 1]; pbz[p] = bv[o + 2];
        pix[p] = po[o + 0]; piy[p] = po[o + 1]; piz[p] = po[o + 2];
        pd[p]  = dk[p];
    }

    float hx = 0.f, hy = 0.f, hz = 0.f;
    for (int t0 = 0; t0 < SEQ; t0 += PF) {
        #pragma unroll
        for (int p = 0; p < PF; ++p) {
            int t = t0 + p;
            float bx = pbx[p], by = pby[p], bz = pbz[p];
            float ix = pix[p], iy = piy[p], iz = piz[p];
            float d  = pd[p];
            int tn = t + PF;
            if (tn < SEQ) {                      // wave-uniform branch
                size_t o = (size_t)tn * D_MODEL;
                pbx[p] = bv[o + 0]; pby[p] = bv[o + 1]; pbz[p] = bv[o + 2];
                pix[p] = po[o + 0]; piy[p] = po[o + 1]; piz[p] = po[o + 2];
                pd[p]  = dk[tn];
            }
            // quaternion from bivector (off the h dependency chain)
            float n2   = bx * bx + by * by + bz * bz;
            float nrm  = fmaxf(__builtin_sqrtf(n2), 1e-8f);
            float half = 0.5f * nrm;
            float w = __cosf(half);
            float s = __sinf(half) / nrm;
            float qx = s * bz, qy = -s * by, qz = s * bx;   // reversed mapping
            // rotate h
            float tx = 2.f * (qy * hz - qz * hy);
            float ty = 2.f * (qz * hx - qx * hz);
            float tz = 2.f * (qx * hy - qy * hx);
            float rx = hx + w * tx + (qy * tz - qz * ty);
            float ry = hy + w * ty + (qz * tx - qx * tz);
            float rz = hz + w * tz + (qx * ty - qy * tx);
            hx = fmaf(d, rx, ix);
            hy = fmaf(d, ry, iy);
            hz = fmaf(d, rz, iz);
            float* o = po + (size_t)t * D_MODEL;
            o[0] = hx; o[1] = hy; o[2] = hz;
        }
    }
}

// ---------------- Kernel 5: LayerNorm + residual, in place on d_out ----------------
__global__ __launch_bounds__(256) void k_ln(
    const float* __restrict__ x, const float* __restrict__ gamma,
    const float* __restrict__ beta, float* __restrict__ io)
{
    int row = blockIdx.x;
    int i   = threadIdx.x;
    float*       pr = io + (size_t)row * D_MODEL;
    const float* xr = x  + (size_t)row * D_MODEL;
    float h0 = pr[i], h1 = pr[i + 256], h2 = pr[i + 512];
    float s = h0 + h1 + h2;
    float q = h0 * h0 + h1 * h1 + h2 * h2;
    #pragma unroll
    for (int off = 32; off; off >>= 1) { s += __shfl_down(s, off); q += __shfl_down(q, off); }
    __shared__ float sb[8];
    __shared__ float mv[2];
    int wid = i >> 6, lane = i & 63;
    if (lane == 0) { sb[wid] = s; sb[wid + 4] = q; }
    __syncthreads();
    if (i == 0) {
        float S = sb[0] + sb[1] + sb[2] + sb[3];
        float Q = sb[4] + sb[5] + sb[6] + sb[7];
        float mean = S * (1.f / 768.f);
        float var  = Q * (1.f / 768.f) - mean * mean;
        mv[0] = mean; mv[1] = rsqrtf(var + LN_EPS);
    }
    __syncthreads();
    float mean = mv[0], rstd = mv[1];
    pr[i]       = (h0 - mean) * rstd * gamma[i]       + beta[i]       + xr[i];
    pr[i + 256] = (h1 - mean) * rstd * gamma[i + 256] + beta[i + 256] + xr[i + 256];
    pr[i + 512] = (h2 - mean) * rstd * gamma[i + 512] + beta[i + 512] + xr[i + 512];
}

extern "C" void kernel_launch(void* const* d_in, const int* in_sizes, int n_in,
                              void* d_out, int out_size, void* d_ws, size_t ws_size,
                              hipStream_t stream) {
    const float* x     = (const float*)d_in[0];
    const float* W_biv = (const float*)d_in[1];
    const float* b_biv = (const float*)d_in[2];
    const float* W_dec = (const float*)d_in[3];
    const float* b_dec = (const float*)d_in[4];
    const float* W_in  = (const float*)d_in[5];
    const float* b_in  = (const float*)d_in[6];
    const float* gamma = (const float*)d_in[7];
    const float* beta  = (const float*)d_in[8];
    float* out = (float*)d_out;

    // workspace layout (needs ~154 MB)
    char* ws = (char*)d_ws;
    unsigned short* xb   = (unsigned short*)(ws);                 // 50,331,648 B
    unsigned short* Wbb  = (unsigned short*)(ws + 50331648);      //  1,179,648 B
    unsigned short* Wib  = (unsigned short*)(ws + 51511296);      //  1,179,648 B
    float*          decay= (float*)         (ws + 52690944);      //    131,072 B
    float*          biv  = (float*)         (ws + 52822016);      // 100,663,296 B

    (void)in_sizes; (void)n_in; (void)out_size; (void)ws_size;

    k_conv_decay<<<M_ROWS, 256, 0, stream>>>(x, W_dec, b_dec, xb, decay);
    k_conv_w    <<<1152,   256, 0, stream>>>(W_biv, W_in, Wbb, Wib);
    k_gemm_bt   <<<dim3(D_MODEL / BN, M_ROWS / BM), 256, 0, stream>>>(xb, Wbb, b_biv, biv);
    k_gemm_bt   <<<dim3(D_MODEL / BN, M_ROWS / BM), 256, 0, stream>>>(xb, Wib, b_in, out);
    k_scan      <<<64, 64, 0, stream>>>(biv, decay, out);
    k_ln        <<<M_ROWS, 256, 0, stream>>>(x, gamma, beta, out);
}

// Round 2
// 340.023 us; speedup vs baseline: 4.3905x; 4.3905x over previous
//
#include <hip/hip_runtime.h>
#include <stdint.h>

#define D_MODEL 768
#define BATCH   16
#define SEQ     2048
#define M_ROWS  (BATCH * SEQ)   // 32768
#define LN_EPS  1e-5f

#define CHUNKS  64
#define CLEN    (SEQ / CHUNKS)  // 32
#define PFA     8               // prefetch depth, scan phases 1/3
#define PFB     8               // prefetch depth, phase 2

typedef __attribute__((ext_vector_type(4))) float  f32x4;
typedef __attribute__((ext_vector_type(8))) __bf16 bf16x8;

__device__ __forceinline__ unsigned short f2bf(float f) {
    union { float f; uint32_t u; } v; v.f = f;
    uint32_t u = v.u;
    uint32_t r = (u + 0x7FFFu + ((u >> 16) & 1u)) >> 16;   // RNE
    return (unsigned short)r;
}

__device__ __forceinline__ void gload_lds16(const void* g, void* l) {
    __builtin_amdgcn_global_load_lds(
        (const __attribute__((address_space(1))) unsigned int*)g,
        (__attribute__((address_space(3))) unsigned int*)l,
        16, 0, 0);
}

// ---------------- Kernel 1: convert x -> bf16, fused decay GEMV ----------------
__global__ __launch_bounds__(256) void k_conv_decay(
    const float* __restrict__ x, const float* __restrict__ Wd,
    const float* __restrict__ bd, unsigned short* __restrict__ xb,
    float* __restrict__ decay)
{
    int row = blockIdx.x;
    int i   = threadIdx.x;
    const float* xr = x + (size_t)row * D_MODEL;
    float v0 = xr[i], v1 = xr[i + 256], v2 = xr[i + 512];
    unsigned short* xbr = xb + (size_t)row * D_MODEL;
    xbr[i] = f2bf(v0); xbr[i + 256] = f2bf(v1); xbr[i + 512] = f2bf(v2);

    float part = v0 * Wd[i] + v1 * Wd[i + 256] + v2 * Wd[i + 512];
    #pragma unroll
    for (int off = 32; off; off >>= 1) part += __shfl_down(part, off);
    __shared__ float wsum[4];
    int wid = i >> 6, lane = i & 63;
    if (lane == 0) wsum[wid] = part;
    __syncthreads();
    if (i == 0) {
        float s = wsum[0] + wsum[1] + wsum[2] + wsum[3] + bd[0];
        decay[row] = 1.f / (1.f + __expf(-s));
    }
}

// ---------------- Kernel 2: convert both weight matrices to bf16 ----------------
__global__ __launch_bounds__(256) void k_conv_w(
    const float* __restrict__ Wb, const float* __restrict__ Wi,
    unsigned short* __restrict__ WbB, unsigned short* __restrict__ WiB)
{
    const int NW = D_MODEL * D_MODEL;          // 589824
    int g = blockIdx.x * 256 + threadIdx.x;
    int base = g * 4;
    const float* src; unsigned short* dst;
    if (base < NW) { src = Wb + base; dst = WbB + base; }
    else           { base -= NW; src = Wi + base; dst = WiB + base; }
    float4 v = *(const float4*)src;
    ushort4 o;
    o.x = f2bf(v.x); o.y = f2bf(v.y); o.z = f2bf(v.z); o.w = f2bf(v.w);
    *(ushort4*)dst = o;
}

// ---------------- Kernel 3: bf16 MFMA GEMM, C(M,N) = A(M,K) * B(N,K)^T + bias ----------------
#define BM 128
#define BN 128
#define BK 32

__global__ __launch_bounds__(256) void k_gemm_bt(
    const unsigned short* __restrict__ A,   // (M,K) bf16
    const unsigned short* __restrict__ B,   // (N,K) bf16  (== W row-major)
    const float* __restrict__ bias,         // (N)
    float* __restrict__ C)                  // (M,N) f32
{
    const int K = D_MODEL, N = D_MODEL;
    __shared__ unsigned short As[BM * BK];  // 8 KiB
    __shared__ unsigned short Bs[BN * BK];  // 8 KiB

    int tid  = threadIdx.x;
    int wave = tid >> 6, lane = tid & 63;
    int m0 = blockIdx.y * BM, n0 = blockIdx.x * BN;
    int wm = wave >> 1, wn = wave & 1;      // 2x2 wave grid, 64x64 per wave

    f32x4 acc[4][4] = {};

    for (int k0 = 0; k0 < K; k0 += BK) {
        #pragma unroll
        for (int hh = 0; hh < 2; ++hh) {
            int c  = wave * 128 + hh * 64 + lane;
            int r  = c >> 2;
            int k8 = (c & 3) * 8;
            gload_lds16(A + (size_t)(m0 + r) * K + k0 + k8, (char*)As + c * 16);
            gload_lds16(B + (size_t)(n0 + r) * K + k0 + k8, (char*)Bs + c * 16);
        }
        __syncthreads();

        bf16x8 af[4], bfr[4];
        int kl = (lane >> 4) * 8;
        int rl = lane & 15;
        #pragma unroll
        for (int i = 0; i < 4; ++i) {
            af[i]  = *reinterpret_cast<const bf16x8*>(&As[(wm * 64 + i * 16 + rl) * BK + kl]);
            bfr[i] = *reinterpret_cast<const bf16x8*>(&Bs[(wn * 64 + i * 16 + rl) * BK + kl]);
        }
        #pragma unroll
        for (int i = 0; i < 4; ++i)
            #pragma unroll
            for (int j = 0; j < 4; ++j)
                acc[i][j] = __builtin_amdgcn_mfma_f32_16x16x32_bf16(af[i], bfr[j], acc[i][j], 0, 0, 0);
        __syncthreads();
    }

    int cl = lane & 15;
    int rg = (lane >> 4) * 4;
    #pragma unroll
    for (int j = 0; j < 4; ++j) {
        int col = n0 + wn * 64 + j * 16 + cl;
        float bs = bias[col];
        #pragma unroll
        for (int i = 0; i < 4; ++i) {
            int rowb = m0 + wm * 64 + i * 16 + rg;
            #pragma unroll
            for (int r = 0; r < 4; ++r)
                C[(size_t)(rowb + r) * N + col] = acc[i][j][r] + bs;
        }
    }
}

// ---------------- Scan phase 1: per-(chain,chunk) local scan from h=0 + operator compose ----
// thread gid -> j = gid&255 (fast, coalesced), c = (gid>>8)&63, b = gid>>14
__global__ __launch_bounds__(256, 4) void k_scan_p1(
    const float* __restrict__ biv, const float* __restrict__ decay,
    float* __restrict__ io,           // in: inj; out: h^0 (local scan from 0), in place
    float* __restrict__ ops)          // per (b,c,j): {Qw,Qx,Qy,Qz,S,bx,by,bz}
{
    int gid = blockIdx.x * 256 + threadIdx.x;
    int j = gid & 255;
    int c = (gid >> 8) & (CHUNKS - 1);
    int b = gid >> 14;
    size_t rowbase = ((size_t)b * SEQ + c * CLEN) * D_MODEL + (size_t)j * 3;
    const float* bv = biv + rowbase;
    float*       po = io  + rowbase;
    const float* dk = decay + b * SEQ + c * CLEN;

    float pbx[PFA], pby[PFA], pbz[PFA], pix[PFA], piy[PFA], piz[PFA], pd[PFA];
    #pragma unroll
    for (int p = 0; p < PFA; ++p) {
        size_t o = (size_t)p * D_MODEL;
        pbx[p] = bv[o]; pby[p] = bv[o + 1]; pbz[p] = bv[o + 2];
        pix[p] = po[o]; piy[p] = po[o + 1]; piz[p] = po[o + 2];
        pd[p]  = dk[p];
    }

    float hx = 0.f, hy = 0.f, hz = 0.f;
    float Qw = 1.f, Qx = 0.f, Qy = 0.f, Qz = 0.f, S = 1.f;
    for (int t0 = 0; t0 < CLEN; t0 += PFA) {
        #pragma unroll
        for (int p = 0; p < PFA; ++p) {
            int t = t0 + p;
            float bx = pbx[p], by = pby[p], bz = pbz[p];
            float ix = pix[p], iy = piy[p], iz = piz[p];
            float d  = pd[p];
            int tn = t + PFA;
            if (tn < CLEN) {
                size_t o = (size_t)tn * D_MODEL;
                pbx[p] = bv[o]; pby[p] = bv[o + 1]; pbz[p] = bv[o + 2];
                pix[p] = po[o]; piy[p] = po[o + 1]; piz[p] = po[o + 2];
                pd[p]  = dk[tn];
            }
            float n2   = bx * bx + by * by + bz * bz;
            float nrm  = fmaxf(__builtin_sqrtf(n2), 1e-8f);
            float half = 0.5f * nrm;
            float w = __cosf(half);
            float s = __sinf(half) / nrm;
            float qx = s * bz, qy = -s * by, qz = s * bx;   // reversed mapping
            // rotate h
            float tx = 2.f * (qy * hz - qz * hy);
            float ty = 2.f * (qz * hx - qx * hz);
            float tz = 2.f * (qx * hy - qy * hx);
            float rx = hx + w * tx + (qy * tz - qz * ty);
            float ry = hy + w * ty + (qz * tx - qx * tz);
            float rz = hz + w * tz + (qx * ty - qy * tx);
            hx = fmaf(d, rx, ix);
            hy = fmaf(d, ry, iy);
            hz = fmaf(d, rz, iz);
            float* o2 = po + (size_t)t * D_MODEL;
            o2[0] = hx; o2[1] = hy; o2[2] = hz;
            // compose total operator: Q <- q_step (x) Q ; S <- d*S
            float nQw = w * Qw - qx * Qx - qy * Qy - qz * Qz;
            float nQx = w * Qx + Qw * qx + (qy * Qz - qz * Qy);
            float nQy = w * Qy + Qw * qy + (qz * Qx - qx * Qz);
            float nQz = w * Qz + Qw * qz + (qx * Qy - qy * Qx);
            Qw = nQw; Qx = nQx; Qy = nQy; Qz = nQz;
            S *= d;
        }
    }
    float* op = ops + ((size_t)(b * CHUNKS + c) * 256 + j) * 8;
    op[0] = Qw; op[1] = Qx; op[2] = Qy; op[3] = Qz;
    op[4] = S;  op[5] = hx; op[6] = hy; op[7] = hz;
}

// ---------------- Scan phase 2: sequential fold of 64 chunk operators per chain ----------------
__global__ __launch_bounds__(64) void k_scan_p2(
    const float* __restrict__ ops, float* __restrict__ hs)
{
    int gid = blockIdx.x * 64 + threadIdx.x;   // 0..4095
    int j = gid & 255, b = gid >> 8;

    float q0[PFB], q1[PFB], q2[PFB], q3[PFB], sc[PFB], o0[PFB], o1[PFB], o2[PFB];
    #pragma unroll
    for (int p = 0; p < PFB; ++p) {
        const float* op = ops + ((size_t)(b * CHUNKS + p) * 256 + j) * 8;
        q0[p] = op[0]; q1[p] = op[1]; q2[p] = op[2]; q3[p] = op[3];
        sc[p] = op[4]; o0[p] = op[5]; o1[p] = op[6]; o2[p] = op[7];
    }
    float hx = 0.f, hy = 0.f, hz = 0.f;
    for (int c0 = 0; c0 < CHUNKS; c0 += PFB) {
        #pragma unroll
        for (int p = 0; p < PFB; ++p) {
            int c = c0 + p;
            float* h = hs + ((size_t)(b * CHUNKS + c) * 256 + j) * 3;
            h[0] = hx; h[1] = hy; h[2] = hz;     // h at entry of chunk c
            float w = q0[p], qx = q1[p], qy = q2[p], qz = q3[p];
            float s = sc[p], bx = o0[p], by = o1[p], bz = o2[p];
            int cn = c + PFB;
            if (cn < CHUNKS) {
                const float* op = ops + ((size_t)(b * CHUNKS + cn) * 256 + j) * 8;
                q0[p] = op[0]; q1[p] = op[1]; q2[p] = op[2]; q3[p] = op[3];
                sc[p] = op[4]; o0[p] = op[5]; o1[p] = op[6]; o2[p] = op[7];
            }
            float tx = 2.f * (qy * hz - qz * hy);
            float ty = 2.f * (qz * hx - qx * hz);
            float tz = 2.f * (qx * hy - qy * hx);
            float rx = hx + w * tx + (qy * tz - qz * ty);
            float ry = hy + w * ty + (qz * tx - qx * tz);
            float rz = hz + w * tz + (qx * ty - qy * tx);
            hx = fmaf(s, rx, bx);
            hy = fmaf(s, ry, by);
            hz = fmaf(s, rz, bz);
        }
    }
}

// ---------------- Scan phase 3: propagate h_start through each chunk, finalize ----------------
__global__ __launch_bounds__(256, 4) void k_scan_p3(
    const float* __restrict__ biv, const float* __restrict__ decay,
    const float* __restrict__ hs, float* __restrict__ io)
{
    int gid = blockIdx.x * 256 + threadIdx.x;
    int j = gid & 255;
    int c = (gid >> 8) & (CHUNKS - 1);
    int b = gid >> 14;
    if (c == 0) return;    // chunk 0 started from h=0: io already final (block-uniform exit)
    size_t rowbase = ((size_t)b * SEQ + c * CLEN) * D_MODEL + (size_t)j * 3;
    const float* bv = biv + rowbase;
    float*       po = io  + rowbase;
    const float* dk = decay + b * SEQ + c * CLEN;
    const float* h0 = hs + ((size_t)(b * CHUNKS + c) * 256 + j) * 3;
    float vx = h0[0], vy = h0[1], vz = h0[2];

    float pbx[PFA], pby[PFA], pbz[PFA], phx[PFA], phy[PFA], phz[PFA], pd[PFA];
    #pragma unroll
    for (int p = 0; p < PFA; ++p) {
        size_t o = (size_t)p * D_MODEL;
        pbx[p] = bv[o]; pby[p] = bv[o + 1]; pbz[p] = bv[o + 2];
        phx[p] = po[o]; phy[p] = po[o + 1]; phz[p] = po[o + 2];
        pd[p]  = dk[p];
    }

    for (int t0 = 0; t0 < CLEN; t0 += PFA) {
        #pragma unroll
        for (int p = 0; p < PFA; ++p) {
            int t = t0 + p;
            float bx = pbx[p], by = pby[p], bz = pbz[p];
            float ax = phx[p], ay = phy[p], az = phz[p];
            float d  = pd[p];
            int tn = t + PFA;
            if (tn < CLEN) {
                size_t o = (size_t)tn * D_MODEL;
                pbx[p] = bv[o]; pby[p] = bv[o + 1]; pbz[p] = bv[o + 2];
                phx[p] = po[o]; phy[p] = po[o + 1]; phz[p] = po[o + 2];
                pd[p]  = dk[tn];
            }
            float n2   = bx * bx + by * by + bz * bz;
            float nrm  = fmaxf(__builtin_sqrtf(n2), 1e-8f);
            float half = 0.5f * nrm;
            float w = __cosf(half);
            float s = __sinf(half) / nrm;
            float qx = s * bz, qy = -s * by, qz = s * bx;
            float tx = 2.f * (qy * vz - qz * vy);
            float ty = 2.f * (qz * vx - qx * vz);
            float tz = 2.f * (qx * vy - qy * vx);
            float rx = vx + w * tx + (qy * tz - qz * ty);
            float ry = vy + w * ty + (qz * tx - qx * tz);
            float rz = vz + w * tz + (qx * ty - qy * tx);
            vx = d * rx; vy = d * ry; vz = d * rz;   // v_t = d_t R_t v_{t-1}
            float* o2 = po + (size_t)t * D_MODEL;
            o2[0] = ax + vx; o2[1] = ay + vy; o2[2] = az + vz;
        }
    }
}

// ---------------- Kernel 5: LayerNorm + residual, in place on d_out ----------------
__global__ __launch_bounds__(256) void k_ln(
    const float* __restrict__ x, const float* __restrict__ gamma,
    const float* __restrict__ beta, float* __restrict__ io)
{
    int row = blockIdx.x;
    int i   = threadIdx.x;
    float*       pr = io + (size_t)row * D_MODEL;
    const float* xr = x  + (size_t)row * D_MODEL;
    float h0 = pr[i], h1 = pr[i + 256], h2 = pr[i + 512];
    float s = h0 + h1 + h2;
    float q = h0 * h0 + h1 * h1 + h2 * h2;
    #pragma unroll
    for (int off = 32; off; off >>= 1) { s += __shfl_down(s, off); q += __shfl_down(q, off); }
    __shared__ float sb[8];
    __shared__ float mv[2];
    int wid = i >> 6, lane = i & 63;
    if (lane == 0) { sb[wid] = s; sb[wid + 4] = q; }
    __syncthreads();
    if (i == 0) {
        float S = sb[0] + sb[1] + sb[2] + sb[3];
        float Q = sb[4] + sb[5] + sb[6] + sb[7];
        float mean = S * (1.f / 768.f);
        float var  = Q * (1.f / 768.f) - mean * mean;
        mv[0] = mean; mv[1] = rsqrtf(var + LN_EPS);
    }
    __syncthreads();
    float mean = mv[0], rstd = mv[1];
    pr[i]       = (h0 - mean) * rstd * gamma[i]       + beta[i]       + xr[i];
    pr[i + 256] = (h1 - mean) * rstd * gamma[i + 256] + beta[i + 256] + xr[i + 256];
    pr[i + 512] = (h2 - mean) * rstd * gamma[i + 512] + beta[i + 512] + xr[i + 512];
}

extern "C" void kernel_launch(void* const* d_in, const int* in_sizes, int n_in,
                              void* d_out, int out_size, void* d_ws, size_t ws_size,
                              hipStream_t stream) {
    const float* x     = (const float*)d_in[0];
    const float* W_biv = (const float*)d_in[1];
    const float* b_biv = (const float*)d_in[2];
    const float* W_dec = (const float*)d_in[3];
    const float* b_dec = (const float*)d_in[4];
    const float* W_in  = (const float*)d_in[5];
    const float* b_in  = (const float*)d_in[6];
    const float* gamma = (const float*)d_in[7];
    const float* beta  = (const float*)d_in[8];
    float* out = (float*)d_out;

    // workspace layout (~154 MB)
    char* ws = (char*)d_ws;
    unsigned short* xb    = (unsigned short*)(ws);              // 50,331,648 B (dead after GEMMs)
    unsigned short* Wbb   = (unsigned short*)(ws + 50331648);   //  1,179,648 B
    unsigned short* Wib   = (unsigned short*)(ws + 51511296);   //  1,179,648 B
    float*          decay = (float*)         (ws + 52690944);   //    131,072 B
    float*          biv   = (float*)         (ws + 52822016);   // 100,663,296 B
    // scan scratch reuses the xb region (xb is dead once both GEMMs complete)
    float*          ops   = (float*)(ws);                       //  8,388,608 B (16*64*256*8 f32)
    float*          hs    = (float*)(ws + 8388608);             //  3,145,728 B (16*64*256*3 f32)

    (void)in_sizes; (void)n_in; (void)out_size; (void)ws_size;

    k_conv_decay<<<M_ROWS, 256, 0, stream>>>(x, W_dec, b_dec, xb, decay);
    k_conv_w    <<<1152,   256, 0, stream>>>(W_biv, W_in, Wbb, Wib);
    k_gemm_bt   <<<dim3(D_MODEL / BN, M_ROWS / BM), 256, 0, stream>>>(xb, Wbb, b_biv, biv);
    k_gemm_bt   <<<dim3(D_MODEL / BN, M_ROWS / BM), 256, 0, stream>>>(xb, Wib, b_in, out);
    k_scan_p1   <<<1024, 256, 0, stream>>>(biv, decay, out, ops);
    k_scan_p2   <<<64,   64,  0, stream>>>(ops, hs);
    k_scan_p3   <<<1024, 256, 0, stream>>>(biv, decay, hs, out);
    k_ln        <<<M_ROWS, 256, 0, stream>>>(x, gamma, beta, out);
}